// Round 8
// baseline (888.691 us; speedup 1.0000x reference)
//
#include <hip/hip_runtime.h>

// SparseRoiExtraCut v8: single-pass lookback compaction, INT32 input mode.
//
// ROOT CAUSE of rounds 1-4,7 failures (absmax=512): is_inside on the HIP side
// is int32 (in_sizes are ELEMENT counts: in_sizes[0]/4==200000 proves it), and
// every failing version hardcoded BYTE mode, misreading the first quarter of
// the int32 buffer. Both passing versions (v2,v6) used detect_mode, which
// selects the int32 path. The fused/lookback structures were never the bug.
//
//   1. hipMemsetAsync : zero lookback state + ticket (~12.5 KB)
//   2. compact_lookback: int32 -> bitmask (regs) -> block count -> ticket-
//                        ordered decoupled lookback -> exclusive prefix ->
//                        ordered flat indices (selIdx) + total
//   3. gather_kernel  : grid-stride float4 gather (proven round 6)

#define BS   256                 // threads per block (4 waves)
#define WPT  8                   // 32-bit mask words per thread
#define WPB  (BS*WPT)            // 2048 words per tile = 65536 elems = 256KB
#define FLAG_AGG (1ull<<62)
#define FLAG_PRE (2ull<<62)

__global__ void __launch_bounds__(BS) compact_lookback(
    const uint4* __restrict__ d, long long totalElems, int wordsTotal,
    int numTiles, int max_sel,
    unsigned long long* __restrict__ state,   // [numTiles], zeroed
    int* __restrict__ ticketPtr,              // zeroed
    int* __restrict__ selIdx, int* __restrict__ totalOut)
{
  __shared__ int sh_ticket;
  __shared__ int sh_excl;
  __shared__ int wsum[BS/64];
  const int tid  = threadIdx.x;
  const int lane = tid & 63;
  const int wid  = tid >> 6;

  if (tid == 0) sh_ticket = atomicAdd(ticketPtr, 1);
  __syncthreads();
  const int t     = sh_ticket;
  const int wBase = t * WPB;

  // ---- phase 1: int32 elems -> bitmask in registers, local popcount
  unsigned m[WPT];
  int cnt = 0;
  #pragma unroll
  for (int k = 0; k < WPT; ++k){
    const int w = wBase + k*BS + tid;
    unsigned mm = 0;
    if (w < wordsTotal){
      const long long e0 = (long long)w << 5;      // 32 int32 elems per word
      if (e0 + 31 < totalElems){
        const uint4* base = d + 8*(long long)w;    // 8 uint4 = 32 int32
        #pragma unroll
        for (int q = 0; q < 8; ++q){
          uint4 x = base[q];
          mm |= ((unsigned)(x.x!=0) << (4*q))   | ((unsigned)(x.y!=0) << (4*q+1)) |
                ((unsigned)(x.z!=0) << (4*q+2)) | ((unsigned)(x.w!=0) << (4*q+3));
        }
      } else {
        const unsigned* p32 = (const unsigned*)d;
        for (int b2 = 0; b2 < 32 && e0 + b2 < totalElems; ++b2)
          if (p32[e0 + b2]) mm |= (1u << b2);
      }
    }
    m[k] = mm;
    cnt += __popc(mm);
  }

  // ---- phase 2: block reduce -> tile aggregate
  int red = cnt;
  for (int off = 32; off > 0; off >>= 1) red += __shfl_down(red, off, 64);
  if (lane == 0) wsum[wid] = red;
  __syncthreads();
  const int agg = wsum[0] + wsum[1] + wsum[2] + wsum[3];

  // ---- phase 3: publish + decoupled lookback (wave 0 only)
  if (tid == 0){
    unsigned long long p = (t == 0 ? FLAG_PRE : FLAG_AGG) | (unsigned long long)(unsigned)agg;
    __hip_atomic_store(&state[t], p, __ATOMIC_RELEASE, __HIP_MEMORY_SCOPE_AGENT);
    if (t == 0){
      sh_excl = 0;
      if (numTiles == 1) *totalOut = agg;
    }
  }
  if (t > 0 && wid == 0){
    int run = 0;          // meaningful in lane 0 only
    int j = t - 1;
    while (true){
      const int idx = j - lane;        // lane 0 reads the newest predecessor
      unsigned long long s;
      if (idx >= 0){
        s = __hip_atomic_load(&state[idx], __ATOMIC_ACQUIRE, __HIP_MEMORY_SCOPE_AGENT);
        while (s == 0ull){
          __builtin_amdgcn_s_sleep(2);   // back off: don't starve publishers
          s = __hip_atomic_load(&state[idx], __ATOMIC_ACQUIRE, __HIP_MEMORY_SCOPE_AGENT);
        }
      } else {
        s = FLAG_PRE;                  // virtual prefix 0 before tile 0
      }
      const unsigned long long ball = __ballot((s >> 62) == 2ull);
      const int val = (int)(s & 0xFFFFFFFFull);
      int contrib;
      int stop = 0;
      if (ball){
        const int firstPre = __ffsll((long long)ball) - 1;   // nearest PREFIX
        contrib = (lane <= firstPre) ? val : 0;
        stop = 1;
      } else {
        contrib = val;                 // window all AGG: take all, keep walking
      }
      for (int off = 32; off > 0; off >>= 1) contrib += __shfl_down(contrib, off, 64);
      if (lane == 0) run += contrib;
      if (stop) break;
      j -= 64;
    }
    if (lane == 0){
      sh_excl = run;
      __hip_atomic_store(&state[t],
                         FLAG_PRE | (unsigned long long)(unsigned)(run + agg),
                         __ATOMIC_RELEASE, __HIP_MEMORY_SCOPE_AGENT);
      if (t == numTiles - 1) *totalOut = run + agg;
    }
  }
  __syncthreads();

  // ---- phase 4: block scan per word-row, emit ordered indices
  int running = sh_excl;
  #pragma unroll
  for (int k = 0; k < WPT; ++k){
    unsigned mm = m[k];
    const int c = __popc(mm);
    int incl = c;
    for (int off = 1; off < 64; off <<= 1){
      int tv = __shfl_up(incl, off, 64);
      if (lane >= off) incl += tv;
    }
    if (lane == 63) wsum[wid] = incl;
    __syncthreads();
    int wbase = 0;
    for (int ww = 0; ww < wid; ++ww) wbase += wsum[ww];
    int iterTotal = 0;
    for (int ww = 0; ww < BS/64; ++ww) iterTotal += wsum[ww];
    int pos = running + wbase + incl - c;
    if (mm){
      const int w = wBase + k*BS + tid;
      const long long e0 = (long long)w << 5;
      while (mm){
        const int b = __ffs(mm) - 1;
        mm &= mm - 1;
        if (pos < max_sel) selIdx[pos] = (int)(e0 + b);
        ++pos;
      }
    }
    running += iterTotal;
    __syncthreads();
  }
}

// grid-stride, 2048 blocks, total clamped once per thread (proven round 6).
__global__ void __launch_bounds__(BS) gather_kernel(
    const int* __restrict__ selIdx, const int* __restrict__ totalPtr,
    const int4* __restrict__ coords, const float4* __restrict__ feat,
    int num_coords, int c4, int max_sel,
    float4* __restrict__ outExt, float4* __restrict__ outFeat)
{
  const int lane    = threadIdx.x & 31;
  const int g0      = (blockIdx.x*blockDim.x + threadIdx.x) >> 5;
  const int gstride = (gridDim.x*blockDim.x) >> 5;
  int total = *totalPtr;
  if (total > max_sel) total = max_sel;
  const float4 z = make_float4(0.f, 0.f, 0.f, 0.f);
  for (int r = g0; r < max_sel; r += gstride){
    float4* dst = outFeat + (long long)r*c4;
    if (r < total){
      const int flat = selIdx[r];
      const unsigned box = (unsigned)flat / (unsigned)num_coords;
      const int ci = flat - (int)box*num_coords;
      const float4* src = feat + (long long)ci*c4;
      for (int c = lane; c < c4; c += 32) dst[c] = src[c];
      if (lane == 0){
        int4 cc = coords[ci];
        outExt[r] = make_float4((float)cc.x, (float)cc.y, (float)cc.z, (float)box);
      }
    } else {
      for (int c = lane; c < c4; c += 32) dst[c] = z;
      if (lane == 0) outExt[r] = z;
    }
  }
}

extern "C" void kernel_launch(void* const* d_in, const int* in_sizes, int n_in,
                              void* d_out, int out_size, void* d_ws, size_t ws_size,
                              hipStream_t stream){
  const int*   coords   = (const int*)d_in[0];
  const float* features = (const float*)d_in[1];
  const void*  inside   = d_in[2];

  const int num_coords = in_sizes[0] / 4;              // 200000
  const int C          = in_sizes[1] / num_coords;     // 128
  const int c4         = C / 4;                        // 32
  const long long totalElems = (long long)in_sizes[2]; // 102,400,000 int32 elems
  const int max_sel    = out_size / (4 + C);           // 262144

  const int wordsTotal = (int)((totalElems + 31) / 32);   // 3,200,000
  const int numTiles   = (wordsTotal + WPB - 1) / WPB;    // 1563

  // workspace layout (8B aligned): state[numTiles] | ticket | total | selIdx
  unsigned long long* state = (unsigned long long*)d_ws;
  int* ticket = (int*)(state + numTiles);
  int* total  = ticket + 1;
  int* selIdx = ticket + 2;

  hipMemsetAsync(state, 0, (size_t)numTiles*8 + 8, stream);   // state + ticket

  hipLaunchKernelGGL(compact_lookback, dim3(numTiles), dim3(BS), 0, stream,
                     (const uint4*)inside, totalElems, wordsTotal, numTiles, max_sel,
                     state, ticket, selIdx, total);

  hipLaunchKernelGGL(gather_kernel, dim3(2048), dim3(BS), 0, stream,
                     selIdx, total, (const int4*)coords, (const float4*)features,
                     num_coords, c4, max_sel,
                     (float4*)d_out,
                     (float4*)((float*)d_out + (long long)max_sel*4));
}

// Round 9
// 681.111 us; speedup vs baseline: 1.3048x; 1.3048x over previous
//
#include <hip/hip_runtime.h>

// SparseRoiExtraCut v9: single-pass lookback compaction, int32 input,
// RELAXED state atomics (v8 delta: remove acquire/release cache maintenance).
//
// v8 (ACQUIRE/RELEASE) passed but compact_lookback ran 420us at 6% HBM /
// 3.5% VALU: the ~19K agent-scope ACQUIRE polls each emit L1-invalidates,
// destroying the L1 reuse phase 1's 128B-per-lane pattern depends on.
// The 64-bit state word is self-contained (flag|prefix in one atomic word;
// selIdx/total consumed only after the kernel boundary), so RELAXED ordering
// is sufficient for correctness and emits no cache-maintenance instructions.
//
//   1. hipMemsetAsync : zero lookback state + ticket (~12.5 KB)
//   2. compact_lookback: int32 -> bitmask (regs) -> ticket-ordered decoupled
//                        lookback -> ordered flat indices (selIdx) + total
//   3. gather_kernel  : grid-stride float4 gather (proven round 6)

#define BS   256                 // threads per block (4 waves)
#define WPT  8                   // 32-bit mask words per thread
#define WPB  (BS*WPT)            // 2048 words per tile = 65536 elems = 256KB
#define FLAG_AGG (1ull<<62)
#define FLAG_PRE (2ull<<62)

__global__ void __launch_bounds__(BS) compact_lookback(
    const uint4* __restrict__ d, long long totalElems, int wordsTotal,
    int numTiles, int max_sel,
    unsigned long long* __restrict__ state,   // [numTiles], zeroed
    int* __restrict__ ticketPtr,              // zeroed
    int* __restrict__ selIdx, int* __restrict__ totalOut)
{
  __shared__ int sh_ticket;
  __shared__ int sh_excl;
  __shared__ int wsum[BS/64];
  const int tid  = threadIdx.x;
  const int lane = tid & 63;
  const int wid  = tid >> 6;

  if (tid == 0) sh_ticket = atomicAdd(ticketPtr, 1);
  __syncthreads();
  const int t     = sh_ticket;
  const int wBase = t * WPB;

  // ---- phase 1: int32 elems -> bitmask in registers, local popcount
  unsigned m[WPT];
  int cnt = 0;
  #pragma unroll
  for (int k = 0; k < WPT; ++k){
    const int w = wBase + k*BS + tid;
    unsigned mm = 0;
    if (w < wordsTotal){
      const long long e0 = (long long)w << 5;      // 32 int32 elems per word
      if (e0 + 31 < totalElems){
        const uint4* base = d + 8*(long long)w;    // 8 uint4 = 32 int32
        #pragma unroll
        for (int q = 0; q < 8; ++q){
          uint4 x = base[q];
          mm |= ((unsigned)(x.x!=0) << (4*q))   | ((unsigned)(x.y!=0) << (4*q+1)) |
                ((unsigned)(x.z!=0) << (4*q+2)) | ((unsigned)(x.w!=0) << (4*q+3));
        }
      } else {
        const unsigned* p32 = (const unsigned*)d;
        for (int b2 = 0; b2 < 32 && e0 + b2 < totalElems; ++b2)
          if (p32[e0 + b2]) mm |= (1u << b2);
      }
    }
    m[k] = mm;
    cnt += __popc(mm);
  }

  // ---- phase 2: block reduce -> tile aggregate
  int red = cnt;
  for (int off = 32; off > 0; off >>= 1) red += __shfl_down(red, off, 64);
  if (lane == 0) wsum[wid] = red;
  __syncthreads();
  const int agg = wsum[0] + wsum[1] + wsum[2] + wsum[3];

  // ---- phase 3: publish + decoupled lookback (wave 0 only), ALL RELAXED
  if (tid == 0){
    unsigned long long p = (t == 0 ? FLAG_PRE : FLAG_AGG) | (unsigned long long)(unsigned)agg;
    __hip_atomic_store(&state[t], p, __ATOMIC_RELAXED, __HIP_MEMORY_SCOPE_AGENT);
    if (t == 0){
      sh_excl = 0;
      if (numTiles == 1) *totalOut = agg;
    }
  }
  if (t > 0 && wid == 0){
    int run = 0;          // meaningful in lane 0 only
    int j = t - 1;
    while (true){
      const int idx = j - lane;        // lane 0 reads the newest predecessor
      unsigned long long s;
      if (idx >= 0){
        s = __hip_atomic_load(&state[idx], __ATOMIC_RELAXED, __HIP_MEMORY_SCOPE_AGENT);
        while (s == 0ull){
          __builtin_amdgcn_s_sleep(2);   // back off: don't starve publishers
          s = __hip_atomic_load(&state[idx], __ATOMIC_RELAXED, __HIP_MEMORY_SCOPE_AGENT);
        }
      } else {
        s = FLAG_PRE;                  // virtual prefix 0 before tile 0
      }
      const unsigned long long ball = __ballot((s >> 62) == 2ull);
      const int val = (int)(s & 0xFFFFFFFFull);
      int contrib;
      int stop = 0;
      if (ball){
        const int firstPre = __ffsll((long long)ball) - 1;   // nearest PREFIX
        contrib = (lane <= firstPre) ? val : 0;
        stop = 1;
      } else {
        contrib = val;                 // window all AGG: take all, keep walking
      }
      for (int off = 32; off > 0; off >>= 1) contrib += __shfl_down(contrib, off, 64);
      if (lane == 0) run += contrib;
      if (stop) break;
      j -= 64;
    }
    if (lane == 0){
      sh_excl = run;
      __hip_atomic_store(&state[t],
                         FLAG_PRE | (unsigned long long)(unsigned)(run + agg),
                         __ATOMIC_RELAXED, __HIP_MEMORY_SCOPE_AGENT);
      if (t == numTiles - 1) *totalOut = run + agg;
    }
  }
  __syncthreads();

  // ---- phase 4: block scan per word-row, emit ordered indices
  int running = sh_excl;
  #pragma unroll
  for (int k = 0; k < WPT; ++k){
    unsigned mm = m[k];
    const int c = __popc(mm);
    int incl = c;
    for (int off = 1; off < 64; off <<= 1){
      int tv = __shfl_up(incl, off, 64);
      if (lane >= off) incl += tv;
    }
    if (lane == 63) wsum[wid] = incl;
    __syncthreads();
    int wbase = 0;
    for (int ww = 0; ww < wid; ++ww) wbase += wsum[ww];
    int iterTotal = 0;
    for (int ww = 0; ww < BS/64; ++ww) iterTotal += wsum[ww];
    int pos = running + wbase + incl - c;
    if (mm){
      const int w = wBase + k*BS + tid;
      const long long e0 = (long long)w << 5;
      while (mm){
        const int b = __ffs(mm) - 1;
        mm &= mm - 1;
        if (pos < max_sel) selIdx[pos] = (int)(e0 + b);
        ++pos;
      }
    }
    running += iterTotal;
    __syncthreads();
  }
}

// grid-stride, 2048 blocks, total clamped once per thread (proven round 6).
__global__ void __launch_bounds__(BS) gather_kernel(
    const int* __restrict__ selIdx, const int* __restrict__ totalPtr,
    const int4* __restrict__ coords, const float4* __restrict__ feat,
    int num_coords, int c4, int max_sel,
    float4* __restrict__ outExt, float4* __restrict__ outFeat)
{
  const int lane    = threadIdx.x & 31;
  const int g0      = (blockIdx.x*blockDim.x + threadIdx.x) >> 5;
  const int gstride = (gridDim.x*blockDim.x) >> 5;
  int total = *totalPtr;
  if (total > max_sel) total = max_sel;
  const float4 z = make_float4(0.f, 0.f, 0.f, 0.f);
  for (int r = g0; r < max_sel; r += gstride){
    float4* dst = outFeat + (long long)r*c4;
    if (r < total){
      const int flat = selIdx[r];
      const unsigned box = (unsigned)flat / (unsigned)num_coords;
      const int ci = flat - (int)box*num_coords;
      const float4* src = feat + (long long)ci*c4;
      for (int c = lane; c < c4; c += 32) dst[c] = src[c];
      if (lane == 0){
        int4 cc = coords[ci];
        outExt[r] = make_float4((float)cc.x, (float)cc.y, (float)cc.z, (float)box);
      }
    } else {
      for (int c = lane; c < c4; c += 32) dst[c] = z;
      if (lane == 0) outExt[r] = z;
    }
  }
}

extern "C" void kernel_launch(void* const* d_in, const int* in_sizes, int n_in,
                              void* d_out, int out_size, void* d_ws, size_t ws_size,
                              hipStream_t stream){
  const int*   coords   = (const int*)d_in[0];
  const float* features = (const float*)d_in[1];
  const void*  inside   = d_in[2];

  const int num_coords = in_sizes[0] / 4;              // 200000
  const int C          = in_sizes[1] / num_coords;     // 128
  const int c4         = C / 4;                        // 32
  const long long totalElems = (long long)in_sizes[2]; // 102,400,000 int32 elems
  const int max_sel    = out_size / (4 + C);           // 262144

  const int wordsTotal = (int)((totalElems + 31) / 32);   // 3,200,000
  const int numTiles   = (wordsTotal + WPB - 1) / WPB;    // 1563

  // workspace layout (8B aligned): state[numTiles] | ticket | total | selIdx
  unsigned long long* state = (unsigned long long*)d_ws;
  int* ticket = (int*)(state + numTiles);
  int* total  = ticket + 1;
  int* selIdx = ticket + 2;

  hipMemsetAsync(state, 0, (size_t)numTiles*8 + 8, stream);   // state + ticket

  hipLaunchKernelGGL(compact_lookback, dim3(numTiles), dim3(BS), 0, stream,
                     (const uint4*)inside, totalElems, wordsTotal, numTiles, max_sel,
                     state, ticket, selIdx, total);

  hipLaunchKernelGGL(gather_kernel, dim3(2048), dim3(BS), 0, stream,
                     selIdx, total, (const int4*)coords, (const float4*)features,
                     num_coords, c4, max_sel,
                     (float4*)d_out,
                     (float4*)((float*)d_out + (long long)max_sel*4));
}

// Round 10
// 662.703 us; speedup vs baseline: 1.3410x; 1.0278x over previous
//
#include <hip/hip_runtime.h>

// SparseRoiExtraCut v10: deterministic 3-kernel pipeline, int32 input.
//   1. pack_count : int32 flags -> 32-bit masks (12.8 MB) + per-block popcounts
//   2. emit_kernel: inline exclusive prefix over counts[] (L2-hot) -> ordered
//                   flat indices (selIdx); last block writes total
//   3. gather_kernel: grid-stride float4 gather (2048 blocks, proven v6)
//
// History: absmax=512 failures (v3b/v4/v5/v7) were ALL the byte-mode bug
// (is_inside is int32; in_sizes are element counts). v8/v9 proved the int32
// path; v9 proved the lookback is correct but SLOWER than a split pipeline
// (all 1563 tiles co-resident => lookback spin buys nothing, costs ~20us).
// So: deterministic split, detect and scan kernels removed.

#define BS  256      // threads per block (4 waves)
#define WPT 8        // mask words per thread
#define WPB (BS*WPT) // 2048 words per block tile = 65536 int32 elems

__global__ void __launch_bounds__(BS) pack_count(
    const uint4* __restrict__ d, long long totalElems, int wordsTotal,
    unsigned* __restrict__ maskOut, int* __restrict__ counts)
{
  const int tid = threadIdx.x;
  const int wBase = blockIdx.x * WPB;
  int cnt = 0;
  #pragma unroll
  for (int k = 0; k < WPT; ++k){
    const int w = wBase + k*BS + tid;
    if (w >= wordsTotal) break;
    const long long e0 = (long long)w << 5;      // 32 int32 elems per word
    unsigned m = 0;
    if (e0 + 31 < totalElems){
      const uint4* base = d + 8*(long long)w;    // 8 uint4 = 32 int32
      #pragma unroll
      for (int q = 0; q < 8; ++q){
        uint4 x = base[q];
        m |= ((unsigned)(x.x!=0) << (4*q))   | ((unsigned)(x.y!=0) << (4*q+1)) |
             ((unsigned)(x.z!=0) << (4*q+2)) | ((unsigned)(x.w!=0) << (4*q+3));
      }
    } else {
      const unsigned* p32 = (const unsigned*)d;
      for (int b2 = 0; b2 < 32 && e0 + b2 < totalElems; ++b2)
        if (p32[e0 + b2]) m |= (1u << b2);
    }
    maskOut[w] = m;
    cnt += __popc(m);
  }
  const int lane = tid & 63, wid = tid >> 6;
  for (int off = 32; off > 0; off >>= 1) cnt += __shfl_down(cnt, off, 64);
  __shared__ int wsum[BS/64];
  if (lane == 0) wsum[wid] = cnt;
  __syncthreads();
  if (tid == 0)
    counts[blockIdx.x] = wsum[0] + wsum[1] + wsum[2] + wsum[3];
}

__global__ void __launch_bounds__(BS) emit_kernel(
    const unsigned* __restrict__ mask, const int* __restrict__ counts,
    int wordsTotal, int numTiles, int max_sel,
    int* __restrict__ outIdx, int* __restrict__ totalOut)
{
  const int tid = threadIdx.x;
  const int lane = tid & 63, wid = tid >> 6;
  const int bid = blockIdx.x;
  __shared__ int wsum[BS/64];
  __shared__ int sh_base;

  // ---- inline exclusive prefix: sum counts[0..bid-1] (L2-hot, <=6.3 KB)
  int pre = 0;
  for (int i = tid; i < bid; i += BS) pre += counts[i];
  int red = pre;
  for (int off = 32; off > 0; off >>= 1) red += __shfl_down(red, off, 64);
  if (lane == 0) wsum[wid] = red;
  __syncthreads();
  if (tid == 0){
    const int base = wsum[0] + wsum[1] + wsum[2] + wsum[3];
    sh_base = base;
    if (bid == numTiles - 1) *totalOut = base + counts[bid];
  }
  __syncthreads();

  // ---- ordered emit of this tile's set bits
  int running = sh_base;
  const int wBase = bid * WPB;
  #pragma unroll
  for (int it = 0; it < WPT; ++it){
    const int w = wBase + it*BS + tid;
    unsigned m = (w < wordsTotal) ? mask[w] : 0u;
    const int cnt = __popc(m);
    int incl = cnt;
    for (int off = 1; off < 64; off <<= 1){
      int t = __shfl_up(incl, off, 64);
      if (lane >= off) incl += t;
    }
    if (lane == 63) wsum[wid] = incl;
    __syncthreads();
    int wbase = 0;
    for (int ww = 0; ww < wid; ++ww) wbase += wsum[ww];
    int iterTotal = 0;
    for (int ww = 0; ww < BS/64; ++ww) iterTotal += wsum[ww];
    int pos = running + wbase + incl - cnt;
    if (m){
      const long long e0 = (long long)w << 5;
      unsigned mm = m;
      while (mm){
        const int b = __ffs(mm) - 1;
        mm &= mm - 1;
        if (pos < max_sel) outIdx[pos] = (int)(e0 + b);
        ++pos;
      }
    }
    running += iterTotal;
    __syncthreads();
  }
}

// grid-stride, 2048 blocks, total clamped once per thread (proven round 6).
__global__ void __launch_bounds__(BS) gather_kernel(
    const int* __restrict__ selIdx, const int* __restrict__ totalPtr,
    const int4* __restrict__ coords, const float4* __restrict__ feat,
    int num_coords, int c4, int max_sel,
    float4* __restrict__ outExt, float4* __restrict__ outFeat)
{
  const int lane    = threadIdx.x & 31;
  const int g0      = (blockIdx.x*blockDim.x + threadIdx.x) >> 5;
  const int gstride = (gridDim.x*blockDim.x) >> 5;
  int total = *totalPtr;
  if (total > max_sel) total = max_sel;
  const float4 z = make_float4(0.f, 0.f, 0.f, 0.f);
  for (int r = g0; r < max_sel; r += gstride){
    float4* dst = outFeat + (long long)r*c4;
    if (r < total){
      const int flat = selIdx[r];
      const unsigned box = (unsigned)flat / (unsigned)num_coords;
      const int ci = flat - (int)box*num_coords;
      const float4* src = feat + (long long)ci*c4;
      for (int c = lane; c < c4; c += 32) dst[c] = src[c];
      if (lane == 0){
        int4 cc = coords[ci];
        outExt[r] = make_float4((float)cc.x, (float)cc.y, (float)cc.z, (float)box);
      }
    } else {
      for (int c = lane; c < c4; c += 32) dst[c] = z;
      if (lane == 0) outExt[r] = z;
    }
  }
}

extern "C" void kernel_launch(void* const* d_in, const int* in_sizes, int n_in,
                              void* d_out, int out_size, void* d_ws, size_t ws_size,
                              hipStream_t stream){
  const int*   coords   = (const int*)d_in[0];
  const float* features = (const float*)d_in[1];
  const void*  inside   = d_in[2];

  const int num_coords = in_sizes[0] / 4;              // 200000
  const int C          = in_sizes[1] / num_coords;     // 128
  const int c4         = C / 4;                        // 32
  const long long totalElems = (long long)in_sizes[2]; // 102,400,000 int32 elems
  const int max_sel    = out_size / (4 + C);           // 262144

  const int wordsTotal = (int)((totalElems + 31) / 32);   // 3,200,000
  const int numTiles   = (wordsTotal + WPB - 1) / WPB;    // 1563

  // workspace layout: counts[numTiles] | total | selIdx[max_sel] | maskBuf
  int* counts  = (int*)d_ws;
  int* total   = counts + numTiles;
  int* selIdx  = total + 1;
  unsigned* maskBuf = (unsigned*)(selIdx + max_sel);

  hipLaunchKernelGGL(pack_count, dim3(numTiles), dim3(BS), 0, stream,
                     (const uint4*)inside, totalElems, wordsTotal, maskBuf, counts);

  hipLaunchKernelGGL(emit_kernel, dim3(numTiles), dim3(BS), 0, stream,
                     maskBuf, counts, wordsTotal, numTiles, max_sel, selIdx, total);

  hipLaunchKernelGGL(gather_kernel, dim3(2048), dim3(BS), 0, stream,
                     selIdx, total, (const int4*)coords, (const float4*)features,
                     num_coords, c4, max_sel,
                     (float4*)d_out,
                     (float4*)((float*)d_out + (long long)max_sel*4));
}

// Round 11
// 662.695 us; speedup vs baseline: 1.3410x; 1.0000x over previous
//
#include <hip/hip_runtime.h>

// SparseRoiExtraCut v11: 2-kernel pipeline, int32 input, fused emit+gather.
//   1. pack_count  : int32 flags -> 32-bit masks (12.8 MB) + per-block popcounts
//   2. emit_gather : tile blocks:  inline exclusive prefix over counts[] ->
//                    emit flats to LDS slots -> in-block warp-per-row gather
//                    of rows [base, base+cnt)  (LDS CAP=2048/tile, expected
//                    ~131; correct global-overflow fallback);
//                    tail blocks:  compute total from counts, zero-fill
//                    [total, max_sel) CONCURRENTLY with tile blocks.
//
// History: absmax=512 failures were the byte-mode bug (is_inside is int32;
// in_sizes are element counts). Lookback (v8/v9) correct but slower than the
// split (all tiles co-resident => spin buys nothing). v10 (3-kernel split,
// 662.7us) is the proven base; this fuses emit+gather and overlaps the
// zero-tail to remove one dispatch + the selIdx round-trip + serialization.

#define BS    256      // threads per block (4 waves)
#define WPT   8        // mask words per thread
#define WPB   (BS*WPT) // 2048 words per block tile = 65536 int32 elems
#define CAP   2048     // LDS flat-slot capacity per tile (expected ~131)
#define TAILB 256      // tail zero-fill blocks

__global__ void __launch_bounds__(BS) pack_count(
    const uint4* __restrict__ d, long long totalElems, int wordsTotal,
    unsigned* __restrict__ maskOut, int* __restrict__ counts)
{
  const int tid = threadIdx.x;
  const int wBase = blockIdx.x * WPB;
  int cnt = 0;
  #pragma unroll
  for (int k = 0; k < WPT; ++k){
    const int w = wBase + k*BS + tid;
    if (w >= wordsTotal) break;
    const long long e0 = (long long)w << 5;      // 32 int32 elems per word
    unsigned m = 0;
    if (e0 + 31 < totalElems){
      const uint4* base = d + 8*(long long)w;    // 8 uint4 = 32 int32
      #pragma unroll
      for (int q = 0; q < 8; ++q){
        uint4 x = base[q];
        m |= ((unsigned)(x.x!=0) << (4*q))   | ((unsigned)(x.y!=0) << (4*q+1)) |
             ((unsigned)(x.z!=0) << (4*q+2)) | ((unsigned)(x.w!=0) << (4*q+3));
      }
    } else {
      const unsigned* p32 = (const unsigned*)d;
      for (int b2 = 0; b2 < 32 && e0 + b2 < totalElems; ++b2)
        if (p32[e0 + b2]) m |= (1u << b2);
    }
    maskOut[w] = m;
    cnt += __popc(m);
  }
  const int lane = tid & 63, wid = tid >> 6;
  for (int off = 32; off > 0; off >>= 1) cnt += __shfl_down(cnt, off, 64);
  __shared__ int wsum[BS/64];
  if (lane == 0) wsum[wid] = cnt;
  __syncthreads();
  if (tid == 0)
    counts[blockIdx.x] = wsum[0] + wsum[1] + wsum[2] + wsum[3];
}

__global__ void __launch_bounds__(BS) emit_gather(
    const unsigned* __restrict__ mask, const int* __restrict__ counts,
    int wordsTotal, int numTiles, int max_sel,
    const int4* __restrict__ coords, const float4* __restrict__ feat,
    int num_coords, int c4,
    int* __restrict__ selOvf,               // global overflow slots (unused in practice)
    float4* __restrict__ outExt, float4* __restrict__ outFeat)
{
  const int tid = threadIdx.x;
  const int lane = tid & 63, wid = tid >> 6;
  const int bid = blockIdx.x;
  __shared__ int wsum[BS/64];
  __shared__ int sh_base;
  __shared__ int ldsFlat[CAP];
  const int w32 = tid >> 5, l32 = tid & 31;   // 32-lane warp decomposition

  if (bid >= numTiles){
    // ---- tail blocks: compute total, zero-fill rows [total, max_sel)
    int pre = 0;
    for (int i = tid; i < numTiles; i += BS) pre += counts[i];
    int red = pre;
    for (int off = 32; off > 0; off >>= 1) red += __shfl_down(red, off, 64);
    if (lane == 0) wsum[wid] = red;
    __syncthreads();
    int total = wsum[0] + wsum[1] + wsum[2] + wsum[3];
    if (total > max_sel) total = max_sel;
    const int tailWarps = TAILB * (BS >> 5);
    const int gw = (bid - numTiles)*(BS >> 5) + w32;
    const float4 z = make_float4(0.f, 0.f, 0.f, 0.f);
    for (int r = total + gw; r < max_sel; r += tailWarps){
      float4* dst = outFeat + (long long)r*c4;
      for (int c = l32; c < c4; c += 32) dst[c] = z;
      if (l32 == 0) outExt[r] = z;
    }
    return;
  }

  // ---- inline exclusive prefix: sum counts[0..bid-1] (L2-hot)
  int pre = 0;
  for (int i = tid; i < bid; i += BS) pre += counts[i];
  int red = pre;
  for (int off = 32; off > 0; off >>= 1) red += __shfl_down(red, off, 64);
  if (lane == 0) wsum[wid] = red;
  __syncthreads();
  if (tid == 0) sh_base = wsum[0] + wsum[1] + wsum[2] + wsum[3];
  __syncthreads();
  const int base = sh_base;

  // ---- ordered emit of this tile's set bits into LDS slots
  int running = base;
  const int wBase = bid * WPB;
  #pragma unroll
  for (int it = 0; it < WPT; ++it){
    const int w = wBase + it*BS + tid;
    unsigned m = (w < wordsTotal) ? mask[w] : 0u;
    const int cnt = __popc(m);
    int incl = cnt;
    for (int off = 1; off < 64; off <<= 1){
      int t = __shfl_up(incl, off, 64);
      if (lane >= off) incl += t;
    }
    if (lane == 63) wsum[wid] = incl;
    __syncthreads();
    int wbase2 = 0;
    for (int ww = 0; ww < wid; ++ww) wbase2 += wsum[ww];
    int iterTotal = 0;
    for (int ww = 0; ww < BS/64; ++ww) iterTotal += wsum[ww];
    int pos = running + wbase2 + incl - cnt;
    if (m){
      const long long e0 = (long long)w << 5;
      unsigned mm = m;
      while (mm){
        const int b = __ffs(mm) - 1;
        mm &= mm - 1;
        const int slot = pos - base;
        if (slot < CAP) ldsFlat[slot] = (int)(e0 + b);
        else if (pos < max_sel) selOvf[pos] = (int)(e0 + b);
        ++pos;
      }
    }
    running += iterTotal;
    __syncthreads();
  }

  // ---- in-block gather: rows [base, base+tileCnt), clamped to max_sel
  const int tileCnt = running - base;          // == counts[bid]
  int nRows = max_sel - base;
  if (nRows > tileCnt) nRows = tileCnt;
  for (int s = w32; s < nRows; s += (BS >> 5)){
    const int flat = (s < CAP) ? ldsFlat[s] : selOvf[base + s];
    const int r = base + s;
    const unsigned box = (unsigned)flat / (unsigned)num_coords;
    const int ci = flat - (int)box*num_coords;
    const float4* src = feat + (long long)ci*c4;
    float4* dst = outFeat + (long long)r*c4;
    for (int c = l32; c < c4; c += 32) dst[c] = src[c];
    if (l32 == 0){
      int4 cc = coords[ci];
      outExt[r] = make_float4((float)cc.x, (float)cc.y, (float)cc.z, (float)box);
    }
  }
}

extern "C" void kernel_launch(void* const* d_in, const int* in_sizes, int n_in,
                              void* d_out, int out_size, void* d_ws, size_t ws_size,
                              hipStream_t stream){
  const int*   coords   = (const int*)d_in[0];
  const float* features = (const float*)d_in[1];
  const void*  inside   = d_in[2];

  const int num_coords = in_sizes[0] / 4;              // 200000
  const int C          = in_sizes[1] / num_coords;     // 128
  const int c4         = C / 4;                        // 32
  const long long totalElems = (long long)in_sizes[2]; // 102,400,000 int32 elems
  const int max_sel    = out_size / (4 + C);           // 262144

  const int wordsTotal = (int)((totalElems + 31) / 32);   // 3,200,000
  const int numTiles   = (wordsTotal + WPB - 1) / WPB;    // 1563

  // workspace layout: counts[numTiles] | selOvf[max_sel] | maskBuf[wordsTotal]
  int* counts  = (int*)d_ws;
  int* selOvf  = counts + numTiles;
  unsigned* maskBuf = (unsigned*)(selOvf + max_sel);

  hipLaunchKernelGGL(pack_count, dim3(numTiles), dim3(BS), 0, stream,
                     (const uint4*)inside, totalElems, wordsTotal, maskBuf, counts);

  hipLaunchKernelGGL(emit_gather, dim3(numTiles + TAILB), dim3(BS), 0, stream,
                     maskBuf, counts, wordsTotal, numTiles, max_sel,
                     (const int4*)coords, (const float4*)features,
                     num_coords, c4, selOvf,
                     (float4*)d_out,
                     (float4*)((float*)d_out + (long long)max_sel*4));
}